// Round 2
// baseline (25990.256 us; speedup 1.0000x reference)
//
#include <hip/hip_runtime.h>
#include <hip/hip_cooperative_groups.h>

namespace cg = cooperative_groups;

#define L_SEQ 1024
#define NB 8
#define DM 1024
#define HHID 512
#define GG 2048   // 4*H == out row stride (2048)

__device__ __forceinline__ float bf2f(unsigned short h) {
    return __uint_as_float(((unsigned)h) << 16);
}
__device__ __forceinline__ unsigned short f2bf(float f) {
    unsigned u = __float_as_uint(f);
    unsigned r = (u + 0x7fffu + ((u >> 16) & 1u)) >> 16;
    return (unsigned short)r;
}

// ---------------------------------------------------------------------------
// Generic NT GEMM: C(bf16)[m][n] = act( sum_k A[m][k]*B[n][k] + bias[n] )
// A: f32 row-major (lda), B: f32 row-major (ldb), K fixed = 1024.
// grid = (N/128, M/128), block = 256, 8x8 microtile.
// ---------------------------------------------------------------------------
__global__ __launch_bounds__(256)
void gemm_nt(const float* __restrict__ A, int lda,
             const float* __restrict__ B, int ldb,
             const float* __restrict__ bias,
             unsigned short* __restrict__ C, int ldc,
             int relu)
{
    __shared__ float As[16][132];
    __shared__ float Bs[16][132];
    const int tid = threadIdx.x;
    const int m0 = blockIdx.y * 128, n0 = blockIdx.x * 128;
    const int tx = tid & 15, ty = tid >> 4;
    const int ar = tid >> 1, ak = (tid & 1) * 8;
    float acc[8][8] = {};
    for (int k0 = 0; k0 < 1024; k0 += 16) {
        float4 a0 = *(const float4*)(A + (size_t)(m0 + ar) * lda + k0 + ak);
        float4 a1 = *(const float4*)(A + (size_t)(m0 + ar) * lda + k0 + ak + 4);
        float4 b0 = *(const float4*)(B + (size_t)(n0 + ar) * ldb + k0 + ak);
        float4 b1 = *(const float4*)(B + (size_t)(n0 + ar) * ldb + k0 + ak + 4);
        __syncthreads();   // previous-iter LDS reads done before overwrite
        As[ak+0][ar]=a0.x; As[ak+1][ar]=a0.y; As[ak+2][ar]=a0.z; As[ak+3][ar]=a0.w;
        As[ak+4][ar]=a1.x; As[ak+5][ar]=a1.y; As[ak+6][ar]=a1.z; As[ak+7][ar]=a1.w;
        Bs[ak+0][ar]=b0.x; Bs[ak+1][ar]=b0.y; Bs[ak+2][ar]=b0.z; Bs[ak+3][ar]=b0.w;
        Bs[ak+4][ar]=b1.x; Bs[ak+5][ar]=b1.y; Bs[ak+6][ar]=b1.z; Bs[ak+7][ar]=b1.w;
        __syncthreads();
        #pragma unroll
        for (int kk = 0; kk < 16; ++kk) {
            float a[8], b[8];
            *(float4*)&a[0] = *(const float4*)&As[kk][ty*8];
            *(float4*)&a[4] = *(const float4*)&As[kk][ty*8+4];
            *(float4*)&b[0] = *(const float4*)&Bs[kk][tx*8];
            *(float4*)&b[4] = *(const float4*)&Bs[kk][tx*8+4];
            #pragma unroll
            for (int i = 0; i < 8; ++i)
                #pragma unroll
                for (int j = 0; j < 8; ++j)
                    acc[i][j] = fmaf(a[i], b[j], acc[i][j]);
        }
    }
    #pragma unroll
    for (int i = 0; i < 8; ++i) {
        int gm = m0 + ty*8 + i;
        #pragma unroll
        for (int j = 0; j < 8; ++j) {
            int gn = n0 + tx*8 + j;
            float v = acc[i][j] + bias[gn];
            if (relu) v = fmaxf(v, 0.f);
            C[(size_t)gm * ldc + gn] = f2bf(v);
        }
    }
}

// ---------------------------------------------------------------------------
// Cooperative bi-LSTM recurrence.
// 128 blocks x 256 threads. block = (dir 0/1) x (64 WGs of 8 hidden units).
// Wave w = gate type (i,f,g,o); lane = (batch(l>>3), unit(l&7)).
// Whh slice (32 rows x 512) lives in LDS as float4 [k4][row].
// h double-buffer parked in d_out's (not yet written) attention half,
// rows 0..15:  addr = (f>>10)*2048 + 1024 + (f&1023). Attention overwrites
// those cells only after the LSTM completes (stream-ordered).
// ---------------------------------------------------------------------------
__global__ __launch_bounds__(256)
void lstm_coop(const float* __restrict__ Whh_f, const float* __restrict__ Whh_b,
               const unsigned short* __restrict__ xWf,
               const unsigned short* __restrict__ xWb,
               float* __restrict__ outp)
{
    cg::grid_group grid = cg::this_grid();
    __shared__ float4 Wlds[128*32];      // [k4][row] 64 KB
    __shared__ float4 h4[8*129];         // [batch][k4] padded (129 f4 stride)
    __shared__ float  gates_lds[4][64];

    const int tid = threadIdx.x;
    const int bx  = blockIdx.x;
    const int dir = bx >> 6;
    const int wg  = bx & 63;
    const int hu0 = wg * 8;
    const float* Whh = dir ? Whh_b : Whh_f;
    const unsigned short* xW = dir ? xWb : xWf;
    const int w = tid >> 6, l = tid & 63;
    const int idx = l & 7, batch = l >> 3;
    const int r_local = w * 8 + idx;     // 0..31

    // preload weight slice (coalesced global float4)
    for (int i = tid; i < 32 * 128; i += 256) {
        int r = i >> 7, k4 = i & 127;
        int grow = (r >> 3) * 512 + hu0 + (r & 7);
        Wlds[k4 * 32 + r] = *(const float4*)(Whh + (size_t)grow * 512 + k4 * 4);
    }
    float c_reg = 0.f;   // used by wave 0 lanes only
    __syncthreads();

    for (int t = 0; t < L_SEQ; ++t) {
        const int t_eff = dir ? (L_SEQ - 1 - t) : t;
        if (t > 0) {
            const int base = (dir * 2 + (t & 1)) * 4096;
            #pragma unroll
            for (int v = 0; v < 4; ++v) {
                int flat = (tid + v * 256) * 4;      // f32 index, multiple of 4
                int f = base + flat;
                const float* src = outp + ((size_t)(f >> 10) * 2048 + 1024 + (f & 1023));
                h4[(flat >> 9) * 129 + ((flat >> 2) & 127)] = *(const float4*)src;
            }
        } else {
            #pragma unroll
            for (int v = 0; v < 4; ++v) {
                int flat = (tid + v * 256) * 4;
                h4[(flat >> 9) * 129 + ((flat >> 2) & 127)] = make_float4(0.f, 0.f, 0.f, 0.f);
            }
        }
        __syncthreads();

        float acc0 = 0.f, acc1 = 0.f;
        const float4* wp = Wlds + r_local;
        const float4* hp = h4 + batch * 129;
        #pragma unroll 8
        for (int k4 = 0; k4 < 128; k4 += 2) {
            float4 w0 = wp[(k4    ) * 32];
            float4 hv0 = hp[k4];
            float4 w1 = wp[(k4 + 1) * 32];
            float4 hv1 = hp[k4 + 1];
            acc0 = fmaf(w0.x, hv0.x, fmaf(w0.y, hv0.y, fmaf(w0.z, hv0.z, fmaf(w0.w, hv0.w, acc0))));
            acc1 = fmaf(w1.x, hv1.x, fmaf(w1.y, hv1.y, fmaf(w1.z, hv1.z, fmaf(w1.w, hv1.w, acc1))));
        }
        float g = acc0 + acc1 +
                  bf2f(xW[((size_t)batch * L_SEQ + t_eff) * GG + w * 512 + hu0 + idx]);
        gates_lds[w][l] = g;
        __syncthreads();
        if (w == 0) {
            float gi = gates_lds[0][l], gf = gates_lds[1][l];
            float gc = gates_lds[2][l], go = gates_lds[3][l];
            float i_ = 1.f / (1.f + __expf(-gi));
            float f_ = 1.f / (1.f + __expf(-gf));
            float g_ = tanhf(gc);
            float o_ = 1.f / (1.f + __expf(-go));
            c_reg = f_ * c_reg + i_ * g_;
            float hn = o_ * tanhf(c_reg);
            int f = (dir * 2 + ((t + 1) & 1)) * 4096 + batch * 512 + hu0 + idx;
            outp[(size_t)(f >> 10) * 2048 + 1024 + (f & 1023)] = hn;       // h state
            outp[((size_t)batch * L_SEQ + t_eff) * GG + dir * 512 + hu0 + idx] = hn; // lstm_out
        }
        grid.sync();
    }
}

// ---------------------------------------------------------------------------
// Attention: grid = 4096 = (b, h, qblock of 16 rows), block = 1024 (wave = q-row).
// Q/K/V are bf16 [8192][1024] (ReLU-projected). Scores row (1024) in LDS,
// wave-parallel softmax, qmask + residual fused. Writes d_out cols
// 1024 + hh*128 .. 1024 + hh*128 + 127.
// ---------------------------------------------------------------------------
__global__ __launch_bounds__(1024)
void attn_kernel(const unsigned short* __restrict__ Qb,
                 const unsigned short* __restrict__ Kb,
                 const unsigned short* __restrict__ Vb,
                 float* __restrict__ outp)
{
    __shared__ float Qs[16][132];
    __shared__ float KV[64][129];
    __shared__ float S[16][1028];
    __shared__ float qmS[16];
    const int tid = threadIdx.x;
    const int wv = tid >> 6, l = tid & 63;
    const int bx = blockIdx.x;
    const int qb = bx & 63, hh = (bx >> 6) & 7, b = bx >> 9;
    const int q0 = qb * 16;

    for (int i = tid; i < 16 * 128; i += 1024) {
        int r = i >> 7, d = i & 127;
        Qs[r][d] = bf2f(Qb[((size_t)(b * L_SEQ + q0 + r)) * DM + hh * 128 + d]);
    }
    {   // qmask = sign(|sum_d queries|), queries = lstm_out (left half of d_out)
        const float* qrow = outp + ((size_t)(b * L_SEQ + q0 + wv)) * GG;
        float sm = 0.f;
        #pragma unroll
        for (int j = 0; j < 16; ++j) sm += qrow[l + 64 * j];
        #pragma unroll
        for (int off = 32; off; off >>= 1) sm += __shfl_xor(sm, off);
        if (l == 0) qmS[wv] = (sm != 0.f) ? 1.f : 0.f;
    }
    const float scale = 0.08838834764831845f;  // 1/sqrt(128)
    for (int kt = 0; kt < 16; ++kt) {
        __syncthreads();
        for (int i = tid; i < 64 * 128; i += 1024) {
            int kk = i >> 7, d = i & 127;
            KV[kk][d] = bf2f(Kb[((size_t)(b * L_SEQ + kt * 64 + kk)) * DM + hh * 128 + d]);
        }
        __syncthreads();
        float s = 0.f;
        #pragma unroll 16
        for (int d = 0; d < 128; ++d) s = fmaf(Qs[wv][d], KV[l][d], s);
        S[wv][kt * 64 + l] = s * scale;
    }
    __syncthreads();
    float vals[16], mx = -1e30f;
    #pragma unroll
    for (int j = 0; j < 16; ++j) { vals[j] = S[wv][j * 64 + l]; mx = fmaxf(mx, vals[j]); }
    #pragma unroll
    for (int off = 32; off; off >>= 1) mx = fmaxf(mx, __shfl_xor(mx, off));
    float sum = 0.f;
    #pragma unroll
    for (int j = 0; j < 16; ++j) { vals[j] = __expf(vals[j] - mx); sum += vals[j]; }
    #pragma unroll
    for (int off = 32; off; off >>= 1) sum += __shfl_xor(sum, off);
    float sc = qmS[wv] / sum;
    #pragma unroll
    for (int j = 0; j < 16; ++j) S[wv][j * 64 + l] = vals[j] * sc;

    float o0 = 0.f, o1 = 0.f;
    for (int kt = 0; kt < 16; ++kt) {
        __syncthreads();
        for (int i = tid; i < 64 * 128; i += 1024) {
            int kk = i >> 7, d = i & 127;
            KV[kk][d] = bf2f(Vb[((size_t)(b * L_SEQ + kt * 64 + kk)) * DM + hh * 128 + d]);
        }
        __syncthreads();
        #pragma unroll 8
        for (int kk = 0; kk < 64; ++kk) {
            float p = S[wv][kt * 64 + kk];
            o0 = fmaf(p, KV[kk][l],      o0);
            o1 = fmaf(p, KV[kk][l + 64], o1);
        }
    }
    // epilogue: residual (+ queries slice of THIS head) and store with head offset.
    float* orow = outp + ((size_t)(b * L_SEQ + q0 + wv)) * GG;
    const int c0 = hh * 128;
    o0 += orow[c0 + l];
    o1 += orow[c0 + l + 64];
    orow[1024 + c0 + l]      = o0;
    orow[1024 + c0 + l + 64] = o1;
}

// ---------------------------------------------------------------------------
extern "C" void kernel_launch(void* const* d_in, const int* in_sizes, int n_in,
                              void* d_out, int out_size, void* d_ws, size_t ws_size,
                              hipStream_t stream) {
    const float* x     = (const float*)d_in[0];
    const float* lab   = (const float*)d_in[1];
    const float* Wih_f = (const float*)d_in[2];
    const float* Whh_f = (const float*)d_in[3];
    const float* b_f   = (const float*)d_in[4];
    const float* Wih_b = (const float*)d_in[5];
    const float* Whh_b = (const float*)d_in[6];
    const float* b_b   = (const float*)d_in[7];
    const float* Wq    = (const float*)d_in[8];
    const float* bq    = (const float*)d_in[9];
    const float* Wk    = (const float*)d_in[10];
    const float* bk    = (const float*)d_in[11];
    const float* Wv    = (const float*)d_in[12];
    const float* bv    = (const float*)d_in[13];
    float* outp = (float*)d_out;
    char*  ws   = (char*)d_ws;

    // workspace layout (peak 64 MB):
    //   phase 1/2: xWf bf16 [0,32M), xWb bf16 [32M,64M)
    //   phase 3/4: Kb [0,16M), Vb [16M,32M), Qb [32M,48M)   (reuse)
    unsigned short* xWf = (unsigned short*)(ws);
    unsigned short* xWb = (unsigned short*)(ws + 33554432);
    unsigned short* Kb  = (unsigned short*)(ws);
    unsigned short* Vb  = (unsigned short*)(ws + 16777216);
    unsigned short* Qb  = (unsigned short*)(ws + 33554432);

    dim3 blk(256);
    // xW = x @ Wih^T + b  (both dirs)
    gemm_nt<<<dim3(16, 64), blk, 0, stream>>>(x, 1024, Wih_f, 1024, b_f, xWf, 2048, 0);
    gemm_nt<<<dim3(16, 64), blk, 0, stream>>>(x, 1024, Wih_b, 1024, b_b, xWb, 2048, 0);

    // recurrence (cooperative: 1024 grid syncs)
    void* args[] = { (void*)&Whh_f, (void*)&Whh_b, (void*)&xWf, (void*)&xWb, (void*)&outp };
    hipLaunchCooperativeKernel((const void*)lstm_coop, dim3(128), dim3(256), args, 0, stream);

    // projections (reuse xW space; stream-ordered after LSTM)
    gemm_nt<<<dim3(8, 64), blk, 0, stream>>>(lab,  1024, Wk, 1024, bk, Kb, 1024, 1);
    gemm_nt<<<dim3(8, 64), blk, 0, stream>>>(lab,  1024, Wv, 1024, bv, Vb, 1024, 1);
    gemm_nt<<<dim3(8, 64), blk, 0, stream>>>(outp, 2048, Wq, 1024, bq, Qb, 1024, 1);

    // attention + residual + concat
    attn_kernel<<<dim3(4096), dim3(1024), 0, stream>>>(Qb, Kb, Vb, outp);
}

// Round 3
// 23999.495 us; speedup vs baseline: 1.0830x; 1.0830x over previous
//
#include <hip/hip_runtime.h>

#define L_SEQ 1024
#define NB 8
#define DM 1024
#define HHID 512
#define GG 2048   // 4*H == out row stride (2048)

__device__ __forceinline__ float bf2f(unsigned short h) {
    return __uint_as_float(((unsigned)h) << 16);
}
__device__ __forceinline__ unsigned short f2bf(float f) {
    unsigned u = __float_as_uint(f);
    unsigned r = (u + 0x7fffu + ((u >> 16) & 1u)) >> 16;
    return (unsigned short)r;
}

// ---------------------------------------------------------------------------
// Generic NT GEMM: C(bf16)[m][n] = act( sum_k A[m][k]*B[n][k] + bias[n] )
// A: f32 row-major (lda), B: f32 row-major (ldb), K fixed = 1024.
// grid = (N/128, M/128), block = 256, 8x8 microtile.
// ---------------------------------------------------------------------------
__global__ __launch_bounds__(256)
void gemm_nt(const float* __restrict__ A, int lda,
             const float* __restrict__ B, int ldb,
             const float* __restrict__ bias,
             unsigned short* __restrict__ C, int ldc,
             int relu)
{
    __shared__ float As[16][132];
    __shared__ float Bs[16][132];
    const int tid = threadIdx.x;
    const int m0 = blockIdx.y * 128, n0 = blockIdx.x * 128;
    const int tx = tid & 15, ty = tid >> 4;
    const int ar = tid >> 1, ak = (tid & 1) * 8;
    float acc[8][8] = {};
    for (int k0 = 0; k0 < 1024; k0 += 16) {
        float4 a0 = *(const float4*)(A + (size_t)(m0 + ar) * lda + k0 + ak);
        float4 a1 = *(const float4*)(A + (size_t)(m0 + ar) * lda + k0 + ak + 4);
        float4 b0 = *(const float4*)(B + (size_t)(n0 + ar) * ldb + k0 + ak);
        float4 b1 = *(const float4*)(B + (size_t)(n0 + ar) * ldb + k0 + ak + 4);
        __syncthreads();   // previous-iter LDS reads done before overwrite
        As[ak+0][ar]=a0.x; As[ak+1][ar]=a0.y; As[ak+2][ar]=a0.z; As[ak+3][ar]=a0.w;
        As[ak+4][ar]=a1.x; As[ak+5][ar]=a1.y; As[ak+6][ar]=a1.z; As[ak+7][ar]=a1.w;
        Bs[ak+0][ar]=b0.x; Bs[ak+1][ar]=b0.y; Bs[ak+2][ar]=b0.z; Bs[ak+3][ar]=b0.w;
        Bs[ak+4][ar]=b1.x; Bs[ak+5][ar]=b1.y; Bs[ak+6][ar]=b1.z; Bs[ak+7][ar]=b1.w;
        __syncthreads();
        #pragma unroll
        for (int kk = 0; kk < 16; ++kk) {
            float a[8], b[8];
            *(float4*)&a[0] = *(const float4*)&As[kk][ty*8];
            *(float4*)&a[4] = *(const float4*)&As[kk][ty*8+4];
            *(float4*)&b[0] = *(const float4*)&Bs[kk][tx*8];
            *(float4*)&b[4] = *(const float4*)&Bs[kk][tx*8+4];
            #pragma unroll
            for (int i = 0; i < 8; ++i)
                #pragma unroll
                for (int j = 0; j < 8; ++j)
                    acc[i][j] = fmaf(a[i], b[j], acc[i][j]);
        }
    }
    #pragma unroll
    for (int i = 0; i < 8; ++i) {
        int gm = m0 + ty*8 + i;
        #pragma unroll
        for (int j = 0; j < 8; ++j) {
            int gn = n0 + tx*8 + j;
            float v = acc[i][j] + bias[gn];
            if (relu) v = fmaxf(v, 0.f);
            C[(size_t)gm * ldc + gn] = f2bf(v);
        }
    }
}

// ---------------------------------------------------------------------------
// Cooperative bi-LSTM recurrence.
// 128 blocks x 256 threads. block = (dir 0/1) x (64 WGs of 8 hidden units).
// Wave w = gate type (i,f,g,o); lane = (batch(l>>3), unit(l&7)).
// Whh slice (32 rows x 512) lives in LDS as float4 [k4][row].
// h double-buffer parked in d_out's (not yet written) attention half,
// rows 0..15:  addr = (f>>10)*2048 + 1024 + (f&1023).
// Hand-rolled per-direction barrier (counters in d_out row 16 attn half,
// zeroed by hipMemsetAsync before launch). Cooperative launch guarantees
// co-residency; we do NOT call grid.sync().
// ---------------------------------------------------------------------------
__global__ __launch_bounds__(256)
void lstm_coop(const float* __restrict__ Whh_f, const float* __restrict__ Whh_b,
               const unsigned short* __restrict__ xWf,
               const unsigned short* __restrict__ xWb,
               float* __restrict__ outp)
{
    __shared__ float4 Wlds[128*32];      // [k4][row] 64 KB
    __shared__ float4 h4[8*129];         // [batch][k4] padded (129 f4 stride)
    __shared__ float  gates_lds[4][64];

    const int tid = threadIdx.x;
    const int bx  = blockIdx.x;
    const int dir = bx >> 6;
    const int wg  = bx & 63;
    const int hu0 = wg * 8;
    const float* Whh = dir ? Whh_b : Whh_f;
    const unsigned short* xW = dir ? xWb : xWf;
    const int w = tid >> 6, l = tid & 63;
    const int idx = l & 7, batch = l >> 3;
    const int r_local = w * 8 + idx;     // 0..31

    unsigned* bar = (unsigned*)(outp + 16 * GG + 1024);  // [2] counters

    // preload weight slice (coalesced global float4)
    for (int i = tid; i < 32 * 128; i += 256) {
        int r = i >> 7, k4 = i & 127;
        int grow = (r >> 3) * 512 + hu0 + (r & 7);
        Wlds[k4 * 32 + r] = *(const float4*)(Whh + (size_t)grow * 512 + k4 * 4);
    }
    float c_reg = 0.f;   // used by wave 0 lanes only
    __syncthreads();

    for (int t = 0; t < L_SEQ; ++t) {
        const int t_eff = dir ? (L_SEQ - 1 - t) : t;
        if (t > 0) {
            const int base = (dir * 2 + (t & 1)) * 4096;
            #pragma unroll
            for (int v = 0; v < 4; ++v) {
                int flat = (tid + v * 256) * 4;      // f32 index, multiple of 4
                int f = base + flat;
                const float* src = outp + ((size_t)(f >> 10) * 2048 + 1024 + (f & 1023));
                h4[(flat >> 9) * 129 + ((flat >> 2) & 127)] = *(const float4*)src;
            }
        } else {
            #pragma unroll
            for (int v = 0; v < 4; ++v) {
                int flat = (tid + v * 256) * 4;
                h4[(flat >> 9) * 129 + ((flat >> 2) & 127)] = make_float4(0.f, 0.f, 0.f, 0.f);
            }
        }
        __syncthreads();

        float acc0 = 0.f, acc1 = 0.f;
        const float4* wp = Wlds + r_local;
        const float4* hp = h4 + batch * 129;
        #pragma unroll 8
        for (int k4 = 0; k4 < 128; k4 += 2) {
            float4 w0 = wp[(k4    ) * 32];
            float4 hv0 = hp[k4];
            float4 w1 = wp[(k4 + 1) * 32];
            float4 hv1 = hp[k4 + 1];
            acc0 = fmaf(w0.x, hv0.x, fmaf(w0.y, hv0.y, fmaf(w0.z, hv0.z, fmaf(w0.w, hv0.w, acc0))));
            acc1 = fmaf(w1.x, hv1.x, fmaf(w1.y, hv1.y, fmaf(w1.z, hv1.z, fmaf(w1.w, hv1.w, acc1))));
        }
        float g = acc0 + acc1 +
                  bf2f(xW[((size_t)batch * L_SEQ + t_eff) * GG + w * 512 + hu0 + idx]);
        gates_lds[w][l] = g;
        __syncthreads();
        if (w == 0) {
            float gi = gates_lds[0][l], gf = gates_lds[1][l];
            float gc = gates_lds[2][l], go = gates_lds[3][l];
            float i_ = 1.f / (1.f + __expf(-gi));
            float f_ = 1.f / (1.f + __expf(-gf));
            float g_ = tanhf(gc);
            float o_ = 1.f / (1.f + __expf(-go));
            c_reg = f_ * c_reg + i_ * g_;
            float hn = o_ * tanhf(c_reg);
            int f = (dir * 2 + ((t + 1) & 1)) * 4096 + batch * 512 + hu0 + idx;
            outp[(size_t)(f >> 10) * 2048 + 1024 + (f & 1023)] = hn;       // h state
            outp[((size_t)batch * L_SEQ + t_eff) * GG + dir * 512 + hu0 + idx] = hn; // lstm_out
        }

        if (t < L_SEQ - 1) {
            // ---- hand-rolled per-direction device barrier ----
            __syncthreads();                 // drains vmcnt: h stores complete
            if (tid == 0) {
                __threadfence();             // release to device scope
                __hip_atomic_fetch_add(bar + dir, 1u, __ATOMIC_RELAXED,
                                       __HIP_MEMORY_SCOPE_AGENT);
                const unsigned tgt = 64u * (unsigned)(t + 1);
                while (__hip_atomic_load(bar + dir, __ATOMIC_RELAXED,
                                         __HIP_MEMORY_SCOPE_AGENT) < tgt) {
                    __builtin_amdgcn_s_sleep(1);
                }
            }
            __syncthreads();
            __threadfence();                 // acquire: invalidate stale lines
        }
    }
}

// ---------------------------------------------------------------------------
// Attention: grid = 4096 = (b, h, qblock of 16 rows), block = 1024 (wave = q-row).
// Q/K/V are bf16 [8192][1024] (ReLU-projected). Scores row (1024) in LDS,
// wave-parallel softmax, qmask + residual fused. Writes d_out cols
// 1024 + hh*128 .. 1024 + hh*128 + 127.
// ---------------------------------------------------------------------------
__global__ __launch_bounds__(1024)
void attn_kernel(const unsigned short* __restrict__ Qb,
                 const unsigned short* __restrict__ Kb,
                 const unsigned short* __restrict__ Vb,
                 float* __restrict__ outp)
{
    __shared__ float Qs[16][132];
    __shared__ float KV[64][129];
    __shared__ float S[16][1028];
    __shared__ float qmS[16];
    const int tid = threadIdx.x;
    const int wv = tid >> 6, l = tid & 63;
    const int bx = blockIdx.x;
    const int qb = bx & 63, hh = (bx >> 6) & 7, b = bx >> 9;
    const int q0 = qb * 16;

    for (int i = tid; i < 16 * 128; i += 1024) {
        int r = i >> 7, d = i & 127;
        Qs[r][d] = bf2f(Qb[((size_t)(b * L_SEQ + q0 + r)) * DM + hh * 128 + d]);
    }
    {   // qmask = sign(|sum_d queries|), queries = lstm_out (left half of d_out)
        const float* qrow = outp + ((size_t)(b * L_SEQ + q0 + wv)) * GG;
        float sm = 0.f;
        #pragma unroll
        for (int j = 0; j < 16; ++j) sm += qrow[l + 64 * j];
        #pragma unroll
        for (int off = 32; off; off >>= 1) sm += __shfl_xor(sm, off);
        if (l == 0) qmS[wv] = (sm != 0.f) ? 1.f : 0.f;
    }
    const float scale = 0.08838834764831845f;  // 1/sqrt(128)
    for (int kt = 0; kt < 16; ++kt) {
        __syncthreads();
        for (int i = tid; i < 64 * 128; i += 1024) {
            int kk = i >> 7, d = i & 127;
            KV[kk][d] = bf2f(Kb[((size_t)(b * L_SEQ + kt * 64 + kk)) * DM + hh * 128 + d]);
        }
        __syncthreads();
        float s = 0.f;
        #pragma unroll 16
        for (int d = 0; d < 128; ++d) s = fmaf(Qs[wv][d], KV[l][d], s);
        S[wv][kt * 64 + l] = s * scale;
    }
    __syncthreads();
    float vals[16], mx = -1e30f;
    #pragma unroll
    for (int j = 0; j < 16; ++j) { vals[j] = S[wv][j * 64 + l]; mx = fmaxf(mx, vals[j]); }
    #pragma unroll
    for (int off = 32; off; off >>= 1) mx = fmaxf(mx, __shfl_xor(mx, off));
    float sum = 0.f;
    #pragma unroll
    for (int j = 0; j < 16; ++j) { vals[j] = __expf(vals[j] - mx); sum += vals[j]; }
    #pragma unroll
    for (int off = 32; off; off >>= 1) sum += __shfl_xor(sum, off);
    float sc = qmS[wv] / sum;
    #pragma unroll
    for (int j = 0; j < 16; ++j) S[wv][j * 64 + l] = vals[j] * sc;

    float o0 = 0.f, o1 = 0.f;
    for (int kt = 0; kt < 16; ++kt) {
        __syncthreads();
        for (int i = tid; i < 64 * 128; i += 1024) {
            int kk = i >> 7, d = i & 127;
            KV[kk][d] = bf2f(Vb[((size_t)(b * L_SEQ + kt * 64 + kk)) * DM + hh * 128 + d]);
        }
        __syncthreads();
        #pragma unroll 8
        for (int kk = 0; kk < 64; ++kk) {
            float p = S[wv][kt * 64 + kk];
            o0 = fmaf(p, KV[kk][l],      o0);
            o1 = fmaf(p, KV[kk][l + 64], o1);
        }
    }
    // epilogue: residual (+ queries slice of THIS head) and store with head offset.
    float* orow = outp + ((size_t)(b * L_SEQ + q0 + wv)) * GG;
    const int c0 = hh * 128;
    o0 += orow[c0 + l];
    o1 += orow[c0 + l + 64];
    orow[1024 + c0 + l]      = o0;
    orow[1024 + c0 + l + 64] = o1;
}

// ---------------------------------------------------------------------------
extern "C" void kernel_launch(void* const* d_in, const int* in_sizes, int n_in,
                              void* d_out, int out_size, void* d_ws, size_t ws_size,
                              hipStream_t stream) {
    const float* x     = (const float*)d_in[0];
    const float* lab   = (const float*)d_in[1];
    const float* Wih_f = (const float*)d_in[2];
    const float* Whh_f = (const float*)d_in[3];
    const float* b_f   = (const float*)d_in[4];
    const float* Wih_b = (const float*)d_in[5];
    const float* Whh_b = (const float*)d_in[6];
    const float* b_b   = (const float*)d_in[7];
    const float* Wq    = (const float*)d_in[8];
    const float* bq    = (const float*)d_in[9];
    const float* Wk    = (const float*)d_in[10];
    const float* bk    = (const float*)d_in[11];
    const float* Wv    = (const float*)d_in[12];
    const float* bv    = (const float*)d_in[13];
    float* outp = (float*)d_out;
    char*  ws   = (char*)d_ws;

    // workspace layout (peak 64 MB):
    //   phase 1/2: xWf bf16 [0,32M), xWb bf16 [32M,64M)
    //   phase 3/4: Kb [0,16M), Vb [16M,32M), Qb [32M,48M)   (reuse)
    unsigned short* xWf = (unsigned short*)(ws);
    unsigned short* xWb = (unsigned short*)(ws + 33554432);
    unsigned short* Kb  = (unsigned short*)(ws);
    unsigned short* Vb  = (unsigned short*)(ws + 16777216);
    unsigned short* Qb  = (unsigned short*)(ws + 33554432);

    dim3 blk(256);
    // xW = x @ Wih^T + b  (both dirs)
    gemm_nt<<<dim3(16, 64), blk, 0, stream>>>(x, 1024, Wih_f, 1024, b_f, xWf, 2048, 0);
    gemm_nt<<<dim3(16, 64), blk, 0, stream>>>(x, 1024, Wih_b, 1024, b_b, xWb, 2048, 0);

    // zero the barrier counters (parked in d_out row 16, attn half)
    hipMemsetAsync((void*)(outp + 16 * GG + 1024), 0, 2 * sizeof(unsigned), stream);

    // recurrence (cooperative launch for co-residency; hand-rolled barrier)
    void* args[] = { (void*)&Whh_f, (void*)&Whh_b, (void*)&xWf, (void*)&xWb, (void*)&outp };
    hipLaunchCooperativeKernel((const void*)lstm_coop, dim3(128), dim3(256), args, 0, stream);

    // projections (reuse xW space; stream-ordered after LSTM)
    gemm_nt<<<dim3(8, 64), blk, 0, stream>>>(lab,  1024, Wk, 1024, bk, Kb, 1024, 1);
    gemm_nt<<<dim3(8, 64), blk, 0, stream>>>(lab,  1024, Wv, 1024, bv, Vb, 1024, 1);
    gemm_nt<<<dim3(8, 64), blk, 0, stream>>>(outp, 2048, Wq, 1024, bq, Qb, 1024, 1);

    // attention + residual + concat
    attn_kernel<<<dim3(4096), dim3(1024), 0, stream>>>(Qb, Kb, Vb, outp);
}

// Round 4
// 12499.683 us; speedup vs baseline: 2.0793x; 1.9200x over previous
//
#include <hip/hip_runtime.h>

#define L_SEQ 1024
#define NB 8
#define DM 1024
#define HHID 512
#define GG 2048   // 4*H == out row stride (2048)

__device__ __forceinline__ float bf2f(unsigned short h) {
    return __uint_as_float(((unsigned)h) << 16);
}
__device__ __forceinline__ unsigned short f2bf(float f) {
    unsigned u = __float_as_uint(f);
    unsigned r = (u + 0x7fffu + ((u >> 16) & 1u)) >> 16;
    return (unsigned short)r;
}

// ---------------------------------------------------------------------------
// Generic NT GEMM: C(bf16)[m][n] = act( sum_k A[m][k]*B[n][k] + bias[n] )
// A: f32 row-major (lda), B: f32 row-major (ldb), K fixed = 1024.
// grid = (N/128, M/128), block = 256, 8x8 microtile.
// ---------------------------------------------------------------------------
__global__ __launch_bounds__(256)
void gemm_nt(const float* __restrict__ A, int lda,
             const float* __restrict__ B, int ldb,
             const float* __restrict__ bias,
             unsigned short* __restrict__ C, int ldc,
             int relu)
{
    __shared__ float As[16][132];
    __shared__ float Bs[16][132];
    const int tid = threadIdx.x;
    const int m0 = blockIdx.y * 128, n0 = blockIdx.x * 128;
    const int tx = tid & 15, ty = tid >> 4;
    const int ar = tid >> 1, ak = (tid & 1) * 8;
    float acc[8][8] = {};
    for (int k0 = 0; k0 < 1024; k0 += 16) {
        float4 a0 = *(const float4*)(A + (size_t)(m0 + ar) * lda + k0 + ak);
        float4 a1 = *(const float4*)(A + (size_t)(m0 + ar) * lda + k0 + ak + 4);
        float4 b0 = *(const float4*)(B + (size_t)(n0 + ar) * ldb + k0 + ak);
        float4 b1 = *(const float4*)(B + (size_t)(n0 + ar) * ldb + k0 + ak + 4);
        __syncthreads();   // previous-iter LDS reads done before overwrite
        As[ak+0][ar]=a0.x; As[ak+1][ar]=a0.y; As[ak+2][ar]=a0.z; As[ak+3][ar]=a0.w;
        As[ak+4][ar]=a1.x; As[ak+5][ar]=a1.y; As[ak+6][ar]=a1.z; As[ak+7][ar]=a1.w;
        Bs[ak+0][ar]=b0.x; Bs[ak+1][ar]=b0.y; Bs[ak+2][ar]=b0.z; Bs[ak+3][ar]=b0.w;
        Bs[ak+4][ar]=b1.x; Bs[ak+5][ar]=b1.y; Bs[ak+6][ar]=b1.z; Bs[ak+7][ar]=b1.w;
        __syncthreads();
        #pragma unroll
        for (int kk = 0; kk < 16; ++kk) {
            float a[8], b[8];
            *(float4*)&a[0] = *(const float4*)&As[kk][ty*8];
            *(float4*)&a[4] = *(const float4*)&As[kk][ty*8+4];
            *(float4*)&b[0] = *(const float4*)&Bs[kk][tx*8];
            *(float4*)&b[4] = *(const float4*)&Bs[kk][tx*8+4];
            #pragma unroll
            for (int i = 0; i < 8; ++i)
                #pragma unroll
                for (int j = 0; j < 8; ++j)
                    acc[i][j] = fmaf(a[i], b[j], acc[i][j]);
        }
    }
    #pragma unroll
    for (int i = 0; i < 8; ++i) {
        int gm = m0 + ty*8 + i;
        #pragma unroll
        for (int j = 0; j < 8; ++j) {
            int gn = n0 + tx*8 + j;
            float v = acc[i][j] + bias[gn];
            if (relu) v = fmaxf(v, 0.f);
            C[(size_t)gm * ldc + gn] = f2bf(v);
        }
    }
}

// ---------------------------------------------------------------------------
// Cooperative bi-LSTM recurrence — fence-free MALL protocol.
// 128 blocks x 256 threads. block = (dir 0/1) x (64 WGs of 8 hidden units).
// Wave w = gate type (i,f,g,o); lane = (batch(l>>3), unit(l&7)).
// Whh slice (32 rows x 512) in LDS as float4 [k4][row].
// h double-buffer parked in d_out rows 0..15 attn half (overwritten by attn
// later):  addr = (f>>10)*2048 + 1024 + (f&1023).
// Per-block epoch flags in d_out rows 16..17 attn half, 64B-spaced, zeroed
// by hipMemsetAsync. ALL cross-block traffic uses agent-scope relaxed
// atomics (sc0 sc1 -> coherence point), so NO __threadfence is needed.
// Cooperative launch guarantees co-residency; no grid.sync().
// ---------------------------------------------------------------------------
__global__ __launch_bounds__(256)
void lstm_coop(const float* __restrict__ Whh_f, const float* __restrict__ Whh_b,
               const unsigned short* __restrict__ xWf,
               const unsigned short* __restrict__ xWb,
               float* __restrict__ outp)
{
    __shared__ float4 Wlds[128*32];      // [k4][row] 64 KB
    __shared__ float4 h4[8*129];         // [batch][k4] padded (129 f4 stride)
    __shared__ float  gates_lds[4][64];

    const int tid = threadIdx.x;
    const int bx  = blockIdx.x;
    const int dir = bx >> 6;
    const int wg  = bx & 63;
    const int hu0 = wg * 8;
    const float* Whh = dir ? Whh_b : Whh_f;
    const unsigned short* xW = dir ? xWb : xWf;
    const int w = tid >> 6, l = tid & 63;
    const int idx = l & 7, batch = l >> 3;
    const int r_local = w * 8 + idx;     // 0..31
    float* hs = (float*)h4;

    // flag for global block i: float-index (16+(i>>6))*2048 + 1024 + (i&63)*16
    #define FLAG_IDX(i) ((size_t)(16 + ((i) >> 6)) * 2048 + 1024 + (size_t)((i) & 63) * 16)
    unsigned* flags = (unsigned*)outp;
    unsigned* myflag = flags + FLAG_IDX(bx);

    // preload weight slice (coalesced global float4)
    for (int i = tid; i < 32 * 128; i += 256) {
        int r = i >> 7, k4 = i & 127;
        int grow = (r >> 3) * 512 + hu0 + (r & 7);
        Wlds[k4 * 32 + r] = *(const float4*)(Whh + (size_t)grow * 512 + k4 * 4);
    }
    float c_reg = 0.f;   // used by wave 0 lanes only
    __syncthreads();

    for (int t = 0; t < L_SEQ; ++t) {
        const int t_eff = dir ? (L_SEQ - 1 - t) : t;
        if (t > 0) {
            // ---- wait: all 64 producer blocks of this dir at epoch >= t ----
            if (w == 0) {
                unsigned* fp = flags + FLAG_IDX(dir * 64 + l);
                while (__hip_atomic_load(fp, __ATOMIC_RELAXED,
                                         __HIP_MEMORY_SCOPE_AGENT) < (unsigned)t) {
                    __builtin_amdgcn_s_sleep(1);
                }
            }
            __syncthreads();
            asm volatile("" ::: "memory");
            // ---- load h (16 KB) from MALL as 8B atomic loads ----
            const int base = (dir * 2 + (t & 1)) * 4096;
            #pragma unroll
            for (int v = 0; v < 8; ++v) {
                int j2 = v * 256 + tid;          // 8B unit index (0..2047)
                int f = base + j2 * 2;
                size_t g = (size_t)(f >> 10) * 2048 + 1024 + (f & 1023);
                unsigned long long d = __hip_atomic_load(
                    (const unsigned long long*)(outp + g),
                    __ATOMIC_RELAXED, __HIP_MEMORY_SCOPE_AGENT);
                int j = j2 * 2;
                int bi = j >> 9, k4w = (j >> 2) & 127, c = j & 3;
                hs[(bi * 129 + k4w) * 4 + c]     = __uint_as_float((unsigned)d);
                hs[(bi * 129 + k4w) * 4 + c + 1] = __uint_as_float((unsigned)(d >> 32));
            }
        } else {
            #pragma unroll
            for (int v = 0; v < 4; ++v) {
                int flat = (tid + v * 256) * 4;
                h4[(flat >> 9) * 129 + ((flat >> 2) & 127)] = make_float4(0.f, 0.f, 0.f, 0.f);
            }
        }
        __syncthreads();

        float acc0 = 0.f, acc1 = 0.f;
        const float4* wp = Wlds + r_local;
        const float4* hp = h4 + batch * 129;
        #pragma unroll 8
        for (int k4 = 0; k4 < 128; k4 += 2) {
            float4 w0 = wp[(k4    ) * 32];
            float4 hv0 = hp[k4];
            float4 w1 = wp[(k4 + 1) * 32];
            float4 hv1 = hp[k4 + 1];
            acc0 = fmaf(w0.x, hv0.x, fmaf(w0.y, hv0.y, fmaf(w0.z, hv0.z, fmaf(w0.w, hv0.w, acc0))));
            acc1 = fmaf(w1.x, hv1.x, fmaf(w1.y, hv1.y, fmaf(w1.z, hv1.z, fmaf(w1.w, hv1.w, acc1))));
        }
        float g = acc0 + acc1 +
                  bf2f(xW[((size_t)batch * L_SEQ + t_eff) * GG + w * 512 + hu0 + idx]);
        gates_lds[w][l] = g;
        __syncthreads();
        if (w == 0) {
            float gi = gates_lds[0][l], gf = gates_lds[1][l];
            float gc = gates_lds[2][l], go = gates_lds[3][l];
            float i_ = 1.f / (1.f + __expf(-gi));
            float f_ = 1.f / (1.f + __expf(-gf));
            float g_ = tanhf(gc);
            float o_ = 1.f / (1.f + __expf(-go));
            c_reg = f_ * c_reg + i_ * g_;
            float hn = o_ * tanhf(c_reg);
            // lstm_out (normal cached store; consumed by later kernels)
            outp[((size_t)batch * L_SEQ + t_eff) * GG + dir * 512 + hu0 + idx] = hn;
            if (t < L_SEQ - 1) {
                // h chunk -> MALL (cache-bypassing atomic store)
                int f = (dir * 2 + ((t + 1) & 1)) * 4096 + batch * 512 + hu0 + idx;
                __hip_atomic_store((unsigned*)(outp + ((size_t)(f >> 10) * 2048 + 1024 + (f & 1023))),
                                   __float_as_uint(hn),
                                   __ATOMIC_RELAXED, __HIP_MEMORY_SCOPE_AGENT);
                asm volatile("s_waitcnt vmcnt(0)" ::: "memory");
                if (l == 0) {
                    __hip_atomic_store(myflag, (unsigned)(t + 1),
                                       __ATOMIC_RELAXED, __HIP_MEMORY_SCOPE_AGENT);
                }
            }
        }
        // next iteration's first __syncthreads orders waves 1-3 behind wave 0
    }
    #undef FLAG_IDX
}

// ---------------------------------------------------------------------------
// Attention: grid = 4096 = (b, h, qblock of 16 rows), block = 1024 (wave = q-row).
// Q/K/V are bf16 [8192][1024] (ReLU-projected). Scores row (1024) in LDS,
// wave-parallel softmax, qmask + residual fused. Writes d_out cols
// 1024 + hh*128 .. 1024 + hh*128 + 127.
// ---------------------------------------------------------------------------
__global__ __launch_bounds__(1024)
void attn_kernel(const unsigned short* __restrict__ Qb,
                 const unsigned short* __restrict__ Kb,
                 const unsigned short* __restrict__ Vb,
                 float* __restrict__ outp)
{
    __shared__ float Qs[16][132];
    __shared__ float KV[64][129];
    __shared__ float S[16][1028];
    __shared__ float qmS[16];
    const int tid = threadIdx.x;
    const int wv = tid >> 6, l = tid & 63;
    const int bx = blockIdx.x;
    const int qb = bx & 63, hh = (bx >> 6) & 7, b = bx >> 9;
    const int q0 = qb * 16;

    for (int i = tid; i < 16 * 128; i += 1024) {
        int r = i >> 7, d = i & 127;
        Qs[r][d] = bf2f(Qb[((size_t)(b * L_SEQ + q0 + r)) * DM + hh * 128 + d]);
    }
    {   // qmask = sign(|sum_d queries|), queries = lstm_out (left half of d_out)
        const float* qrow = outp + ((size_t)(b * L_SEQ + q0 + wv)) * GG;
        float sm = 0.f;
        #pragma unroll
        for (int j = 0; j < 16; ++j) sm += qrow[l + 64 * j];
        #pragma unroll
        for (int off = 32; off; off >>= 1) sm += __shfl_xor(sm, off);
        if (l == 0) qmS[wv] = (sm != 0.f) ? 1.f : 0.f;
    }
    const float scale = 0.08838834764831845f;  // 1/sqrt(128)
    for (int kt = 0; kt < 16; ++kt) {
        __syncthreads();
        for (int i = tid; i < 64 * 128; i += 1024) {
            int kk = i >> 7, d = i & 127;
            KV[kk][d] = bf2f(Kb[((size_t)(b * L_SEQ + kt * 64 + kk)) * DM + hh * 128 + d]);
        }
        __syncthreads();
        float s = 0.f;
        #pragma unroll 16
        for (int d = 0; d < 128; ++d) s = fmaf(Qs[wv][d], KV[l][d], s);
        S[wv][kt * 64 + l] = s * scale;
    }
    __syncthreads();
    float vals[16], mx = -1e30f;
    #pragma unroll
    for (int j = 0; j < 16; ++j) { vals[j] = S[wv][j * 64 + l]; mx = fmaxf(mx, vals[j]); }
    #pragma unroll
    for (int off = 32; off; off >>= 1) mx = fmaxf(mx, __shfl_xor(mx, off));
    float sum = 0.f;
    #pragma unroll
    for (int j = 0; j < 16; ++j) { vals[j] = __expf(vals[j] - mx); sum += vals[j]; }
    #pragma unroll
    for (int off = 32; off; off >>= 1) sum += __shfl_xor(sum, off);
    float sc = qmS[wv] / sum;
    #pragma unroll
    for (int j = 0; j < 16; ++j) S[wv][j * 64 + l] = vals[j] * sc;

    float o0 = 0.f, o1 = 0.f;
    for (int kt = 0; kt < 16; ++kt) {
        __syncthreads();
        for (int i = tid; i < 64 * 128; i += 1024) {
            int kk = i >> 7, d = i & 127;
            KV[kk][d] = bf2f(Vb[((size_t)(b * L_SEQ + kt * 64 + kk)) * DM + hh * 128 + d]);
        }
        __syncthreads();
        #pragma unroll 8
        for (int kk = 0; kk < 64; ++kk) {
            float p = S[wv][kt * 64 + kk];
            o0 = fmaf(p, KV[kk][l],      o0);
            o1 = fmaf(p, KV[kk][l + 64], o1);
        }
    }
    // epilogue: residual (+ queries slice of THIS head) and store with head offset.
    float* orow = outp + ((size_t)(b * L_SEQ + q0 + wv)) * GG;
    const int c0 = hh * 128;
    o0 += orow[c0 + l];
    o1 += orow[c0 + l + 64];
    orow[1024 + c0 + l]      = o0;
    orow[1024 + c0 + l + 64] = o1;
}

// ---------------------------------------------------------------------------
extern "C" void kernel_launch(void* const* d_in, const int* in_sizes, int n_in,
                              void* d_out, int out_size, void* d_ws, size_t ws_size,
                              hipStream_t stream) {
    const float* x     = (const float*)d_in[0];
    const float* lab   = (const float*)d_in[1];
    const float* Wih_f = (const float*)d_in[2];
    const float* Whh_f = (const float*)d_in[3];
    const float* b_f   = (const float*)d_in[4];
    const float* Wih_b = (const float*)d_in[5];
    const float* Whh_b = (const float*)d_in[6];
    const float* b_b   = (const float*)d_in[7];
    const float* Wq    = (const float*)d_in[8];
    const float* bq    = (const float*)d_in[9];
    const float* Wk    = (const float*)d_in[10];
    const float* bk    = (const float*)d_in[11];
    const float* Wv    = (const float*)d_in[12];
    const float* bv    = (const float*)d_in[13];
    float* outp = (float*)d_out;
    char*  ws   = (char*)d_ws;

    // workspace layout (peak 64 MB):
    //   phase 1/2: xWf bf16 [0,32M), xWb bf16 [32M,64M)
    //   phase 3/4: Kb [0,16M), Vb [16M,32M), Qb [32M,48M)   (reuse)
    unsigned short* xWf = (unsigned short*)(ws);
    unsigned short* xWb = (unsigned short*)(ws + 33554432);
    unsigned short* Kb  = (unsigned short*)(ws);
    unsigned short* Vb  = (unsigned short*)(ws + 16777216);
    unsigned short* Qb  = (unsigned short*)(ws + 33554432);

    dim3 blk(256);
    // xW = x @ Wih^T + b  (both dirs)
    gemm_nt<<<dim3(16, 64), blk, 0, stream>>>(x, 1024, Wih_f, 1024, b_f, xWf, 2048, 0);
    gemm_nt<<<dim3(16, 64), blk, 0, stream>>>(x, 1024, Wih_b, 1024, b_b, xWb, 2048, 0);

    // zero the per-block epoch flags (d_out rows 16..17, attn half)
    hipMemsetAsync((void*)(outp + 16 * GG + 1024), 0, 4096, stream);
    hipMemsetAsync((void*)(outp + 17 * GG + 1024), 0, 4096, stream);

    // recurrence (cooperative launch for co-residency; fence-free barrier)
    void* args[] = { (void*)&Whh_f, (void*)&Whh_b, (void*)&xWf, (void*)&xWb, (void*)&outp };
    hipLaunchCooperativeKernel((const void*)lstm_coop, dim3(128), dim3(256), args, 0, stream);

    // projections (reuse xW space; stream-ordered after LSTM)
    gemm_nt<<<dim3(8, 64), blk, 0, stream>>>(lab,  1024, Wk, 1024, bk, Kb, 1024, 1);
    gemm_nt<<<dim3(8, 64), blk, 0, stream>>>(lab,  1024, Wv, 1024, bv, Vb, 1024, 1);
    gemm_nt<<<dim3(8, 64), blk, 0, stream>>>(outp, 2048, Wq, 1024, bq, Qb, 1024, 1);

    // attention + residual + concat
    attn_kernel<<<dim3(4096), dim3(1024), 0, stream>>>(Qb, Kb, Vb, outp);
}

// Round 5
// 10725.400 us; speedup vs baseline: 2.4232x; 1.1654x over previous
//
#include <hip/hip_runtime.h>

#define L_SEQ 1024
#define NB 8
#define DM 1024
#define HHID 512
#define GG 2048   // 4*H == out row stride (2048)

__device__ __forceinline__ float bf2f(unsigned short h) {
    return __uint_as_float(((unsigned)h) << 16);
}
__device__ __forceinline__ unsigned short f2bf(float f) {
    unsigned u = __float_as_uint(f);
    unsigned r = (u + 0x7fffu + ((u >> 16) & 1u)) >> 16;
    return (unsigned short)r;
}

// ---------------------------------------------------------------------------
// Generic NT GEMM: C(bf16)[m][n] = act( sum_k A[m][k]*B[n][k] + bias[n] )
// A: f32 row-major (lda), B: f32 row-major (ldb), K fixed = 1024.
// grid = (N/128, M/128), block = 256, 8x8 microtile.
// ---------------------------------------------------------------------------
__global__ __launch_bounds__(256)
void gemm_nt(const float* __restrict__ A, int lda,
             const float* __restrict__ B, int ldb,
             const float* __restrict__ bias,
             unsigned short* __restrict__ C, int ldc,
             int relu)
{
    __shared__ float As[16][132];
    __shared__ float Bs[16][132];
    const int tid = threadIdx.x;
    const int m0 = blockIdx.y * 128, n0 = blockIdx.x * 128;
    const int tx = tid & 15, ty = tid >> 4;
    const int ar = tid >> 1, ak = (tid & 1) * 8;
    float acc[8][8] = {};
    for (int k0 = 0; k0 < 1024; k0 += 16) {
        float4 a0 = *(const float4*)(A + (size_t)(m0 + ar) * lda + k0 + ak);
        float4 a1 = *(const float4*)(A + (size_t)(m0 + ar) * lda + k0 + ak + 4);
        float4 b0 = *(const float4*)(B + (size_t)(n0 + ar) * ldb + k0 + ak);
        float4 b1 = *(const float4*)(B + (size_t)(n0 + ar) * ldb + k0 + ak + 4);
        __syncthreads();   // previous-iter LDS reads done before overwrite
        As[ak+0][ar]=a0.x; As[ak+1][ar]=a0.y; As[ak+2][ar]=a0.z; As[ak+3][ar]=a0.w;
        As[ak+4][ar]=a1.x; As[ak+5][ar]=a1.y; As[ak+6][ar]=a1.z; As[ak+7][ar]=a1.w;
        Bs[ak+0][ar]=b0.x; Bs[ak+1][ar]=b0.y; Bs[ak+2][ar]=b0.z; Bs[ak+3][ar]=b0.w;
        Bs[ak+4][ar]=b1.x; Bs[ak+5][ar]=b1.y; Bs[ak+6][ar]=b1.z; Bs[ak+7][ar]=b1.w;
        __syncthreads();
        #pragma unroll
        for (int kk = 0; kk < 16; ++kk) {
            float a[8], b[8];
            *(float4*)&a[0] = *(const float4*)&As[kk][ty*8];
            *(float4*)&a[4] = *(const float4*)&As[kk][ty*8+4];
            *(float4*)&b[0] = *(const float4*)&Bs[kk][tx*8];
            *(float4*)&b[4] = *(const float4*)&Bs[kk][tx*8+4];
            #pragma unroll
            for (int i = 0; i < 8; ++i)
                #pragma unroll
                for (int j = 0; j < 8; ++j)
                    acc[i][j] = fmaf(a[i], b[j], acc[i][j]);
        }
    }
    #pragma unroll
    for (int i = 0; i < 8; ++i) {
        int gm = m0 + ty*8 + i;
        #pragma unroll
        for (int j = 0; j < 8; ++j) {
            int gn = n0 + tx*8 + j;
            float v = acc[i][j] + bias[gn];
            if (relu) v = fmaxf(v, 0.f);
            C[(size_t)gm * ldc + gn] = f2bf(v);
        }
    }
}

// ---------------------------------------------------------------------------
// Cooperative bi-LSTM recurrence — fence-free MALL protocol + register-W.
// 128 blocks x 256 threads. block = (dir 0/1) x (64 WGs of 8 hidden units).
// Thread (g = wave = gate, s = lane = k-slice): holds Whh[g*512+hu0+u][k]
// for u=0..7, k in {4s..4s+3} u {256+4s..256+4s+3} in 64 VGPRs (loaded once).
// Per step: 16 ds_read_b128 of h + 512 FMA -> acc[u][b]; 6-round shfl_xor
// butterfly reduces over the 64 k-slice lanes; lane l ends with gate value
// for (u=l&7, b=l>>3). Gates exchanged via tiny LDS; wave 0 does
// activations, c-update, h stores.
// h double-buffer parked in d_out rows 0..15 attn half:
//   addr = (f>>10)*2048 + 1024 + (f&1023).
// Per-block epoch flags in d_out rows 16..17 attn half (hipMemsetAsync'd 0).
// ALL cross-block traffic = agent-scope relaxed atomics (MALL, no fences).
// ---------------------------------------------------------------------------
__global__ __launch_bounds__(256, 1)
void lstm_coop(const float* __restrict__ Whh_f, const float* __restrict__ Whh_b,
               const unsigned short* __restrict__ xWf,
               const unsigned short* __restrict__ xWb,
               float* __restrict__ outp)
{
    __shared__ float hs[8 * 512];        // h tile [b][k] f32, 16 KB
    __shared__ float gates_lds[4][64];

    const int tid = threadIdx.x;
    const int bx  = blockIdx.x;
    const int dir = bx >> 6;
    const int wg  = bx & 63;
    const int hu0 = wg * 8;
    const float* Whh = dir ? Whh_b : Whh_f;
    const unsigned short* xW = dir ? xWb : xWf;
    const int g = tid >> 6;              // wave = gate
    const int l = tid & 63;              // lane = k-slice s (compute) / out (reduce)
    const int s = l;
    const int u_o = l & 7, b_o = l >> 3; // output assignment after butterfly
    const float4* hlds4 = (const float4*)hs;

    // flag for global block i: float-index (16+(i>>6))*2048 + 1024 + (i&63)*16
    #define FLAG_IDX(i) ((size_t)(16 + ((i) >> 6)) * 2048 + 1024 + (size_t)((i) & 63) * 16)
    unsigned* flags = (unsigned*)outp;
    unsigned* myflag = flags + FLAG_IDX(bx);

    // ---- preload Whh slice into registers (once) ----
    float4 W0[8], W1[8];                 // [u]: k = 4s..4s+3  /  256+4s..256+4s+3
    #pragma unroll
    for (int u = 0; u < 8; ++u) {
        const float* row = Whh + (size_t)(g * 512 + hu0 + u) * 512;
        W0[u] = *(const float4*)(row + 4 * s);
        W1[u] = *(const float4*)(row + 256 + 4 * s);
    }
    float c_reg = 0.f;                   // wave 0 lanes only

    for (int t = 0; t < L_SEQ; ++t) {
        const int t_eff = dir ? (L_SEQ - 1 - t) : t;
        if (t > 0) {
            // ---- wait: all 64 producer blocks of this dir at epoch >= t ----
            if (g == 0) {
                unsigned* fp = flags + FLAG_IDX(dir * 64 + l);
                while (__hip_atomic_load(fp, __ATOMIC_RELAXED,
                                         __HIP_MEMORY_SCOPE_AGENT) < (unsigned)t) {
                    __builtin_amdgcn_s_sleep(1);
                }
            }
            __syncthreads();
            asm volatile("" ::: "memory");
            // ---- load h (16 KB) from MALL as 8B atomic loads -> LDS ----
            const int base = (dir * 2 + (t & 1)) * 4096;
            #pragma unroll
            for (int v = 0; v < 8; ++v) {
                int j2 = v * 256 + tid;          // 8B unit index (0..2047)
                int f = base + j2 * 2;
                size_t gsrc = (size_t)(f >> 10) * 2048 + 1024 + (f & 1023);
                unsigned long long d = __hip_atomic_load(
                    (const unsigned long long*)(outp + gsrc),
                    __ATOMIC_RELAXED, __HIP_MEMORY_SCOPE_AGENT);
                float2 hv;
                hv.x = __uint_as_float((unsigned)d);
                hv.y = __uint_as_float((unsigned)(d >> 32));
                *(float2*)&hs[j2 * 2] = hv;
            }
        } else {
            #pragma unroll
            for (int v = 0; v < 4; ++v)
                *(float4*)&hs[(v * 256 + tid) * 4] = make_float4(0.f, 0.f, 0.f, 0.f);
        }
        __syncthreads();

        // xW for this thread's eventual output (u_o, b_o) — issue early
        float xw = bf2f(xW[((size_t)b_o * L_SEQ + t_eff) * GG + g * 512 + hu0 + u_o]);

        // ---- partial dot products over this lane's k-slice ----
        float acc[8][8];                 // [u][b]
        #pragma unroll
        for (int u = 0; u < 8; ++u)
            #pragma unroll
            for (int b = 0; b < 8; ++b) acc[u][b] = 0.f;
        #pragma unroll
        for (int b = 0; b < 8; ++b) {
            float4 h1 = hlds4[b * 128 + s];
            float4 h2 = hlds4[b * 128 + 64 + s];
            #pragma unroll
            for (int u = 0; u < 8; ++u) {
                float a = acc[u][b];
                a = fmaf(W0[u].x, h1.x, a);
                a = fmaf(W0[u].y, h1.y, a);
                a = fmaf(W0[u].z, h1.z, a);
                a = fmaf(W0[u].w, h1.w, a);
                a = fmaf(W1[u].x, h2.x, a);
                a = fmaf(W1[u].y, h2.y, a);
                a = fmaf(W1[u].z, h2.z, a);
                a = fmaf(W1[u].w, h2.w, a);
                acc[u][b] = a;
            }
        }

        // ---- butterfly reduce over 64 lanes: out index j = b*8 + u ----
        float red[64];
        #pragma unroll
        for (int u = 0; u < 8; ++u)
            #pragma unroll
            for (int b = 0; b < 8; ++b) red[b * 8 + u] = acc[u][b];
        #pragma unroll
        for (int m = 0; m < 6; ++m) {
            const int bit = 1 << m;
            const bool mine = (l >> m) & 1;
            const int n2 = 32 >> m;
            #pragma unroll
            for (int i = 0; i < n2; ++i) {
                float a0 = red[2 * i], a1 = red[2 * i + 1];
                float keep = mine ? a1 : a0;
                float send = mine ? a0 : a1;
                red[i] = keep + __shfl_xor(send, bit);
            }
        }
        // lane l now holds the full dot for (gate g, unit u_o, batch b_o)
        gates_lds[g][l] = red[0] + xw;
        __syncthreads();

        if (g == 0) {
            float gi = gates_lds[0][l], gf = gates_lds[1][l];
            float gc = gates_lds[2][l], go = gates_lds[3][l];
            float i_ = 1.f / (1.f + __expf(-gi));
            float f_ = 1.f / (1.f + __expf(-gf));
            float g_ = tanhf(gc);
            float o_ = 1.f / (1.f + __expf(-go));
            c_reg = f_ * c_reg + i_ * g_;
            float hn = o_ * tanhf(c_reg);
            // lstm_out (normal cached store; consumed by later kernels)
            outp[((size_t)b_o * L_SEQ + t_eff) * GG + dir * 512 + hu0 + u_o] = hn;
            if (t < L_SEQ - 1) {
                // h chunk -> MALL (cache-bypassing atomic store)
                int f = (dir * 2 + ((t + 1) & 1)) * 4096 + b_o * 512 + hu0 + u_o;
                __hip_atomic_store((unsigned*)(outp + ((size_t)(f >> 10) * 2048 + 1024 + (f & 1023))),
                                   __float_as_uint(hn),
                                   __ATOMIC_RELAXED, __HIP_MEMORY_SCOPE_AGENT);
                asm volatile("s_waitcnt vmcnt(0)" ::: "memory");
                if (l == 0) {
                    __hip_atomic_store(myflag, (unsigned)(t + 1),
                                       __ATOMIC_RELAXED, __HIP_MEMORY_SCOPE_AGENT);
                }
            }
        }
        // next iteration's first __syncthreads orders waves 1-3 behind wave 0
    }
    #undef FLAG_IDX
}

// ---------------------------------------------------------------------------
// Attention: grid = 4096 = (b, h, qblock of 16 rows), block = 1024 (wave = q-row).
// Q/K/V are bf16 [8192][1024] (ReLU-projected). Scores row (1024) in LDS,
// wave-parallel softmax, qmask + residual fused. Writes d_out cols
// 1024 + hh*128 .. 1024 + hh*128 + 127.
// ---------------------------------------------------------------------------
__global__ __launch_bounds__(1024)
void attn_kernel(const unsigned short* __restrict__ Qb,
                 const unsigned short* __restrict__ Kb,
                 const unsigned short* __restrict__ Vb,
                 float* __restrict__ outp)
{
    __shared__ float Qs[16][132];
    __shared__ float KV[64][129];
    __shared__ float S[16][1028];
    __shared__ float qmS[16];
    const int tid = threadIdx.x;
    const int wv = tid >> 6, l = tid & 63;
    const int bx = blockIdx.x;
    const int qb = bx & 63, hh = (bx >> 6) & 7, b = bx >> 9;
    const int q0 = qb * 16;

    for (int i = tid; i < 16 * 128; i += 1024) {
        int r = i >> 7, d = i & 127;
        Qs[r][d] = bf2f(Qb[((size_t)(b * L_SEQ + q0 + r)) * DM + hh * 128 + d]);
    }
    {   // qmask = sign(|sum_d queries|), queries = lstm_out (left half of d_out)
        const float* qrow = outp + ((size_t)(b * L_SEQ + q0 + wv)) * GG;
        float sm = 0.f;
        #pragma unroll
        for (int j = 0; j < 16; ++j) sm += qrow[l + 64 * j];
        #pragma unroll
        for (int off = 32; off; off >>= 1) sm += __shfl_xor(sm, off);
        if (l == 0) qmS[wv] = (sm != 0.f) ? 1.f : 0.f;
    }
    const float scale = 0.08838834764831845f;  // 1/sqrt(128)
    for (int kt = 0; kt < 16; ++kt) {
        __syncthreads();
        for (int i = tid; i < 64 * 128; i += 1024) {
            int kk = i >> 7, d = i & 127;
            KV[kk][d] = bf2f(Kb[((size_t)(b * L_SEQ + kt * 64 + kk)) * DM + hh * 128 + d]);
        }
        __syncthreads();
        float sc = 0.f;
        #pragma unroll 16
        for (int d = 0; d < 128; ++d) sc = fmaf(Qs[wv][d], KV[l][d], sc);
        S[wv][kt * 64 + l] = sc * scale;
    }
    __syncthreads();
    float vals[16], mx = -1e30f;
    #pragma unroll
    for (int j = 0; j < 16; ++j) { vals[j] = S[wv][j * 64 + l]; mx = fmaxf(mx, vals[j]); }
    #pragma unroll
    for (int off = 32; off; off >>= 1) mx = fmaxf(mx, __shfl_xor(mx, off));
    float sum = 0.f;
    #pragma unroll
    for (int j = 0; j < 16; ++j) { vals[j] = __expf(vals[j] - mx); sum += vals[j]; }
    #pragma unroll
    for (int off = 32; off; off >>= 1) sum += __shfl_xor(sum, off);
    float sc = qmS[wv] / sum;
    #pragma unroll
    for (int j = 0; j < 16; ++j) S[wv][j * 64 + l] = vals[j] * sc;

    float o0 = 0.f, o1 = 0.f;
    for (int kt = 0; kt < 16; ++kt) {
        __syncthreads();
        for (int i = tid; i < 64 * 128; i += 1024) {
            int kk = i >> 7, d = i & 127;
            KV[kk][d] = bf2f(Vb[((size_t)(b * L_SEQ + kt * 64 + kk)) * DM + hh * 128 + d]);
        }
        __syncthreads();
        #pragma unroll 8
        for (int kk = 0; kk < 64; ++kk) {
            float p = S[wv][kt * 64 + kk];
            o0 = fmaf(p, KV[kk][l],      o0);
            o1 = fmaf(p, KV[kk][l + 64], o1);
        }
    }
    // epilogue: residual (+ queries slice of THIS head) and store with head offset.
    float* orow = outp + ((size_t)(b * L_SEQ + q0 + wv)) * GG;
    const int c0 = hh * 128;
    o0 += orow[c0 + l];
    o1 += orow[c0 + l + 64];
    orow[1024 + c0 + l]      = o0;
    orow[1024 + c0 + l + 64] = o1;
}

// ---------------------------------------------------------------------------
extern "C" void kernel_launch(void* const* d_in, const int* in_sizes, int n_in,
                              void* d_out, int out_size, void* d_ws, size_t ws_size,
                              hipStream_t stream) {
    const float* x     = (const float*)d_in[0];
    const float* lab   = (const float*)d_in[1];
    const float* Wih_f = (const float*)d_in[2];
    const float* Whh_f = (const float*)d_in[3];
    const float* b_f   = (const float*)d_in[4];
    const float* Wih_b = (const float*)d_in[5];
    const float* Whh_b = (const float*)d_in[6];
    const float* b_b   = (const float*)d_in[7];
    const float* Wq    = (const float*)d_in[8];
    const float* bq    = (const float*)d_in[9];
    const float* Wk    = (const float*)d_in[10];
    const float* bk    = (const float*)d_in[11];
    const float* Wv    = (const float*)d_in[12];
    const float* bv    = (const float*)d_in[13];
    float* outp = (float*)d_out;
    char*  ws   = (char*)d_ws;

    // workspace layout (peak 64 MB):
    //   phase 1/2: xWf bf16 [0,32M), xWb bf16 [32M,64M)
    //   phase 3/4: Kb [0,16M), Vb [16M,32M), Qb [32M,48M)   (reuse)
    unsigned short* xWf = (unsigned short*)(ws);
    unsigned short* xWb = (unsigned short*)(ws + 33554432);
    unsigned short* Kb  = (unsigned short*)(ws);
    unsigned short* Vb  = (unsigned short*)(ws + 16777216);
    unsigned short* Qb  = (unsigned short*)(ws + 33554432);

    dim3 blk(256);
    // xW = x @ Wih^T + b  (both dirs)
    gemm_nt<<<dim3(16, 64), blk, 0, stream>>>(x, 1024, Wih_f, 1024, b_f, xWf, 2048, 0);
    gemm_nt<<<dim3(16, 64), blk, 0, stream>>>(x, 1024, Wih_b, 1024, b_b, xWb, 2048, 0);

    // zero the per-block epoch flags (d_out rows 16..17, attn half)
    hipMemsetAsync((void*)(outp + 16 * GG + 1024), 0, 4096, stream);
    hipMemsetAsync((void*)(outp + 17 * GG + 1024), 0, 4096, stream);

    // recurrence (cooperative launch for co-residency; fence-free barrier)
    void* args[] = { (void*)&Whh_f, (void*)&Whh_b, (void*)&xWf, (void*)&xWb, (void*)&outp };
    hipLaunchCooperativeKernel((const void*)lstm_coop, dim3(128), dim3(256), args, 0, stream);

    // projections (reuse xW space; stream-ordered after LSTM)
    gemm_nt<<<dim3(8, 64), blk, 0, stream>>>(lab,  1024, Wk, 1024, bk, Kb, 1024, 1);
    gemm_nt<<<dim3(8, 64), blk, 0, stream>>>(lab,  1024, Wv, 1024, bv, Vb, 1024, 1);
    gemm_nt<<<dim3(8, 64), blk, 0, stream>>>(outp, 2048, Wq, 1024, bq, Qb, 1024, 1);

    // attention + residual + concat
    attn_kernel<<<dim3(4096), dim3(1024), 0, stream>>>(Qb, Kb, Vb, outp);
}

// Round 6
// 7998.464 us; speedup vs baseline: 3.2494x; 1.3409x over previous
//
#include <hip/hip_runtime.h>

#define L_SEQ 1024
#define NB 8
#define DM 1024
#define HHID 512
#define GG 2048   // out row stride (2048); lstm_out = cols 0..1023

typedef __attribute__((ext_vector_type(8))) short bf16x8;
typedef __attribute__((ext_vector_type(4))) short bf16x4;
typedef __attribute__((ext_vector_type(4))) float f32x4;

__device__ __forceinline__ float bf2f(unsigned short h) {
    return __uint_as_float(((unsigned)h) << 16);
}
__device__ __forceinline__ unsigned short f2bf(float f) {
    unsigned u = __float_as_uint(f);
    unsigned r = (u + 0x7fffu + ((u >> 16) & 1u)) >> 16;
    return (unsigned short)r;
}

// ---------------------------------------------------------------------------
// Generic NT GEMM: C(bf16)[m][n] = act( sum_k A[m][k]*B[n][k] + bias[n] )
// A: f32 row-major (lda), B: f32 row-major (ldb), K fixed = 1024.
// grid = (N/128, M/128), block = 256, 8x8 microtile.
// ---------------------------------------------------------------------------
__global__ __launch_bounds__(256)
void gemm_nt(const float* __restrict__ A, int lda,
             const float* __restrict__ B, int ldb,
             const float* __restrict__ bias,
             unsigned short* __restrict__ C, int ldc,
             int relu)
{
    __shared__ float As[16][132];
    __shared__ float Bs[16][132];
    const int tid = threadIdx.x;
    const int m0 = blockIdx.y * 128, n0 = blockIdx.x * 128;
    const int tx = tid & 15, ty = tid >> 4;
    const int ar = tid >> 1, ak = (tid & 1) * 8;
    float acc[8][8] = {};
    for (int k0 = 0; k0 < 1024; k0 += 16) {
        float4 a0 = *(const float4*)(A + (size_t)(m0 + ar) * lda + k0 + ak);
        float4 a1 = *(const float4*)(A + (size_t)(m0 + ar) * lda + k0 + ak + 4);
        float4 b0 = *(const float4*)(B + (size_t)(n0 + ar) * ldb + k0 + ak);
        float4 b1 = *(const float4*)(B + (size_t)(n0 + ar) * ldb + k0 + ak + 4);
        __syncthreads();   // previous-iter LDS reads done before overwrite
        As[ak+0][ar]=a0.x; As[ak+1][ar]=a0.y; As[ak+2][ar]=a0.z; As[ak+3][ar]=a0.w;
        As[ak+4][ar]=a1.x; As[ak+5][ar]=a1.y; As[ak+6][ar]=a1.z; As[ak+7][ar]=a1.w;
        Bs[ak+0][ar]=b0.x; Bs[ak+1][ar]=b0.y; Bs[ak+2][ar]=b0.z; Bs[ak+3][ar]=b0.w;
        Bs[ak+4][ar]=b1.x; Bs[ak+5][ar]=b1.y; Bs[ak+6][ar]=b1.z; Bs[ak+7][ar]=b1.w;
        __syncthreads();
        #pragma unroll
        for (int kk = 0; kk < 16; ++kk) {
            float a[8], b[8];
            *(float4*)&a[0] = *(const float4*)&As[kk][ty*8];
            *(float4*)&a[4] = *(const float4*)&As[kk][ty*8+4];
            *(float4*)&b[0] = *(const float4*)&Bs[kk][tx*8];
            *(float4*)&b[4] = *(const float4*)&Bs[kk][tx*8+4];
            #pragma unroll
            for (int i = 0; i < 8; ++i)
                #pragma unroll
                for (int j = 0; j < 8; ++j)
                    acc[i][j] = fmaf(a[i], b[j], acc[i][j]);
        }
    }
    #pragma unroll
    for (int i = 0; i < 8; ++i) {
        int gm = m0 + ty*8 + i;
        #pragma unroll
        for (int j = 0; j < 8; ++j) {
            int gn = n0 + tx*8 + j;
            float v = acc[i][j] + bias[gn];
            if (relu) v = fmaxf(v, 0.f);
            C[(size_t)gm * ldc + gn] = f2bf(v);
        }
    }
}

// ---------------------------------------------------------------------------
// Cooperative bi-LSTM recurrence — fence-free MALL protocol + register-W.
// (unchanged from round 5; see comments there)
// ---------------------------------------------------------------------------
__global__ __launch_bounds__(256, 1)
void lstm_coop(const float* __restrict__ Whh_f, const float* __restrict__ Whh_b,
               const unsigned short* __restrict__ xWf,
               const unsigned short* __restrict__ xWb,
               float* __restrict__ outp)
{
    __shared__ float hs[8 * 512];        // h tile [b][k] f32, 16 KB
    __shared__ float gates_lds[4][64];

    const int tid = threadIdx.x;
    const int bx  = blockIdx.x;
    const int dir = bx >> 6;
    const int wg  = bx & 63;
    const int hu0 = wg * 8;
    const float* Whh = dir ? Whh_b : Whh_f;
    const unsigned short* xW = dir ? xWb : xWf;
    const int g = tid >> 6;              // wave = gate
    const int l = tid & 63;              // lane = k-slice s (compute) / out (reduce)
    const int s = l;
    const int u_o = l & 7, b_o = l >> 3; // output assignment after butterfly
    const float4* hlds4 = (const float4*)hs;

    #define FLAG_IDX(i) ((size_t)(16 + ((i) >> 6)) * 2048 + 1024 + (size_t)((i) & 63) * 16)
    unsigned* flags = (unsigned*)outp;
    unsigned* myflag = flags + FLAG_IDX(bx);

    // ---- preload Whh slice into registers (once) ----
    float4 W0[8], W1[8];                 // [u]: k = 4s..4s+3  /  256+4s..256+4s+3
    #pragma unroll
    for (int u = 0; u < 8; ++u) {
        const float* row = Whh + (size_t)(g * 512 + hu0 + u) * 512;
        W0[u] = *(const float4*)(row + 4 * s);
        W1[u] = *(const float4*)(row + 256 + 4 * s);
    }
    float c_reg = 0.f;                   // wave 0 lanes only

    for (int t = 0; t < L_SEQ; ++t) {
        const int t_eff = dir ? (L_SEQ - 1 - t) : t;
        if (t > 0) {
            if (g == 0) {
                unsigned* fp = flags + FLAG_IDX(dir * 64 + l);
                while (__hip_atomic_load(fp, __ATOMIC_RELAXED,
                                         __HIP_MEMORY_SCOPE_AGENT) < (unsigned)t) {
                    __builtin_amdgcn_s_sleep(1);
                }
            }
            __syncthreads();
            asm volatile("" ::: "memory");
            const int base = (dir * 2 + (t & 1)) * 4096;
            #pragma unroll
            for (int v = 0; v < 8; ++v) {
                int j2 = v * 256 + tid;          // 8B unit index (0..2047)
                int f = base + j2 * 2;
                size_t gsrc = (size_t)(f >> 10) * 2048 + 1024 + (f & 1023);
                unsigned long long d = __hip_atomic_load(
                    (const unsigned long long*)(outp + gsrc),
                    __ATOMIC_RELAXED, __HIP_MEMORY_SCOPE_AGENT);
                float2 hv;
                hv.x = __uint_as_float((unsigned)d);
                hv.y = __uint_as_float((unsigned)(d >> 32));
                *(float2*)&hs[j2 * 2] = hv;
            }
        } else {
            #pragma unroll
            for (int v = 0; v < 4; ++v)
                *(float4*)&hs[(v * 256 + tid) * 4] = make_float4(0.f, 0.f, 0.f, 0.f);
        }
        __syncthreads();

        float xw = bf2f(xW[((size_t)b_o * L_SEQ + t_eff) * GG + g * 512 + hu0 + u_o]);

        float acc[8][8];                 // [u][b]
        #pragma unroll
        for (int u = 0; u < 8; ++u)
            #pragma unroll
            for (int b = 0; b < 8; ++b) acc[u][b] = 0.f;
        #pragma unroll
        for (int b = 0; b < 8; ++b) {
            float4 h1 = hlds4[b * 128 + s];
            float4 h2 = hlds4[b * 128 + 64 + s];
            #pragma unroll
            for (int u = 0; u < 8; ++u) {
                float a = acc[u][b];
                a = fmaf(W0[u].x, h1.x, a);
                a = fmaf(W0[u].y, h1.y, a);
                a = fmaf(W0[u].z, h1.z, a);
                a = fmaf(W0[u].w, h1.w, a);
                a = fmaf(W1[u].x, h2.x, a);
                a = fmaf(W1[u].y, h2.y, a);
                a = fmaf(W1[u].z, h2.z, a);
                a = fmaf(W1[u].w, h2.w, a);
                acc[u][b] = a;
            }
        }

        float red[64];
        #pragma unroll
        for (int u = 0; u < 8; ++u)
            #pragma unroll
            for (int b = 0; b < 8; ++b) red[b * 8 + u] = acc[u][b];
        #pragma unroll
        for (int m = 0; m < 6; ++m) {
            const int bit = 1 << m;
            const bool mine = (l >> m) & 1;
            const int n2 = 32 >> m;
            #pragma unroll
            for (int i = 0; i < n2; ++i) {
                float a0 = red[2 * i], a1 = red[2 * i + 1];
                float keep = mine ? a1 : a0;
                float send = mine ? a0 : a1;
                red[i] = keep + __shfl_xor(send, bit);
            }
        }
        gates_lds[g][l] = red[0] + xw;
        __syncthreads();

        if (g == 0) {
            float gi = gates_lds[0][l], gf = gates_lds[1][l];
            float gc = gates_lds[2][l], go = gates_lds[3][l];
            float i_ = 1.f / (1.f + __expf(-gi));
            float f_ = 1.f / (1.f + __expf(-gf));
            float g_ = tanhf(gc);
            float o_ = 1.f / (1.f + __expf(-go));
            c_reg = f_ * c_reg + i_ * g_;
            float hn = o_ * tanhf(c_reg);
            outp[((size_t)b_o * L_SEQ + t_eff) * GG + dir * 512 + hu0 + u_o] = hn;
            if (t < L_SEQ - 1) {
                int f = (dir * 2 + ((t + 1) & 1)) * 4096 + b_o * 512 + hu0 + u_o;
                __hip_atomic_store((unsigned*)(outp + ((size_t)(f >> 10) * 2048 + 1024 + (f & 1023))),
                                   __float_as_uint(hn),
                                   __ATOMIC_RELAXED, __HIP_MEMORY_SCOPE_AGENT);
                asm volatile("s_waitcnt vmcnt(0)" ::: "memory");
                if (l == 0) {
                    __hip_atomic_store(myflag, (unsigned)(t + 1),
                                       __ATOMIC_RELAXED, __HIP_MEMORY_SCOPE_AGENT);
                }
            }
        }
    }
    #undef FLAG_IDX
}

// ---------------------------------------------------------------------------
// MFMA attention: grid = 4096 = (b, hh, 16-q-row tile), block = 256 (4 waves).
// Q staged once (4 a-frags in regs); K/V streamed in 64-row chunks;
// QK^T and PV via mfma_f32_16x16x32_bf16; wave-parallel f32 softmax;
// qmask + residual fused. Writes d_out cols 1024+hh*128 .. +127.
// Frag layout (m89-verified): a[l][j]=A[l&15][(l>>4)*8+j],
// b[l][j]=B[(l>>4)*8+j][l&15], D[l][r]=D[(l>>4)*4+r][l&15].
// ---------------------------------------------------------------------------
__global__ __launch_bounds__(256)
void attn_mfma(const unsigned short* __restrict__ Qb,
               const unsigned short* __restrict__ Kb,
               const unsigned short* __restrict__ Vb,
               float* __restrict__ outp)
{
    __shared__ unsigned short Qs[16][136];    // Q tile, padded
    __shared__ unsigned short KVs[64][140];   // K/V chunk, pad 140 (PV col-gather)
    __shared__ float S[16][1040];             // scores f32
    __shared__ unsigned short Pm[16][1032];   // P bf16
    __shared__ float qmS[16];

    const int tid = threadIdx.x;
    const int w = tid >> 6, l = tid & 63;
    const int lm = l & 15, gq = l >> 4;
    const int bx = blockIdx.x;
    const int qb = bx & 63, hh = (bx >> 6) & 7, b = bx >> 9;
    const int q0 = qb * 16;

    {   // stage Q tile (16 x 128 bf16): one 16B unit per thread
        int row = tid >> 4, d8 = tid & 15;
        *(bf16x8*)&Qs[row][d8 * 8] =
            *(const bf16x8*)(Qb + ((size_t)(b * L_SEQ + q0 + row)) * DM + hh * 128 + d8 * 8);
    }
    // qmask: wave w handles rows w*4..w*4+3 (sum over 1024-dim queries)
    for (int r = 0; r < 4; ++r) {
        int row = w * 4 + r;
        const float* qrow = outp + ((size_t)(b * L_SEQ + q0 + row)) * GG;
        float sm = 0.f;
        #pragma unroll
        for (int j = 0; j < 16; ++j) sm += qrow[l + 64 * j];
        #pragma unroll
        for (int off = 32; off; off >>= 1) sm += __shfl_xor(sm, off);
        if (l == 0) qmS[row] = (sm != 0.f) ? 1.f : 0.f;
    }
    __syncthreads();

    // preload the 4 Q a-frags (d-steps of 32)
    bf16x8 aq[4];
    #pragma unroll
    for (int ds = 0; ds < 4; ++ds)
        aq[ds] = *(const bf16x8*)&Qs[lm][ds * 32 + gq * 8];

    const float scale = 0.08838834764831845f;  // 1/sqrt(128)

    // ---- QK^T: wave w owns k-cols [c*64 + w*16, +16) ----
    for (int c = 0; c < 16; ++c) {
        __syncthreads();
        #pragma unroll
        for (int v = 0; v < 4; ++v) {
            int i = v * 256 + tid, row = i >> 4, d8 = i & 15;
            *(bf16x8*)&KVs[row][d8 * 8] =
                *(const bf16x8*)(Kb + ((size_t)(b * L_SEQ + c * 64 + row)) * DM + hh * 128 + d8 * 8);
        }
        __syncthreads();
        f32x4 acc = {0.f, 0.f, 0.f, 0.f};
        #pragma unroll
        for (int ds = 0; ds < 4; ++ds) {
            const unsigned short* bp = &KVs[w * 16 + lm][ds * 32 + gq * 8];
            bf16x8 bv;
            *(bf16x4*)&bv = *(const bf16x4*)bp;          // rows are 8B-aligned (280B stride)
            *(((bf16x4*)&bv) + 1) = *(const bf16x4*)(bp + 4);
            acc = __builtin_amdgcn_mfma_f32_16x16x32_bf16(aq[ds], bv, acc, 0, 0, 0);
        }
        #pragma unroll
        for (int r = 0; r < 4; ++r)
            S[gq * 4 + r][c * 64 + w * 16 + lm] = acc[r] * scale;
    }
    __syncthreads();

    // ---- softmax rows w*4..w*4+3 -> P bf16 (qmask/sum folded in) ----
    for (int r = 0; r < 4; ++r) {
        int row = w * 4 + r;
        float vals[16], mx = -1e30f;
        #pragma unroll
        for (int j = 0; j < 16; ++j) { vals[j] = S[row][j * 64 + l]; mx = fmaxf(mx, vals[j]); }
        #pragma unroll
        for (int off = 32; off; off >>= 1) mx = fmaxf(mx, __shfl_xor(mx, off));
        float sum = 0.f;
        #pragma unroll
        for (int j = 0; j < 16; ++j) { vals[j] = __expf(vals[j] - mx); sum += vals[j]; }
        #pragma unroll
        for (int off = 32; off; off >>= 1) sum += __shfl_xor(sum, off);
        float sc = qmS[row] / sum;
        #pragma unroll
        for (int j = 0; j < 16; ++j) Pm[row][j * 64 + l] = f2bf(vals[j] * sc);
    }

    // ---- PV: wave w owns d-cols [w*32, w*32+32) ----
    f32x4 o0 = {0.f, 0.f, 0.f, 0.f}, o1 = {0.f, 0.f, 0.f, 0.f};
    for (int c = 0; c < 16; ++c) {
        __syncthreads();   // also guards P writes before first V chunk
        #pragma unroll
        for (int v = 0; v < 4; ++v) {
            int i = v * 256 + tid, row = i >> 4, d8 = i & 15;
            *(bf16x8*)&KVs[row][d8 * 8] =
                *(const bf16x8*)(Vb + ((size_t)(b * L_SEQ + c * 64 + row)) * DM + hh * 128 + d8 * 8);
        }
        __syncthreads();
        #pragma unroll
        for (int ks = 0; ks < 2; ++ks) {
            const int kb = ks * 32 + gq * 8;
            bf16x8 av = *(const bf16x8*)&Pm[lm][c * 64 + kb];
            {
                const int ncol = w * 32 + lm;
                bf16x8 bv;
                #pragma unroll
                for (int j = 0; j < 8; ++j) ((unsigned short*)&bv)[j] = KVs[kb + j][ncol];
                o0 = __builtin_amdgcn_mfma_f32_16x16x32_bf16(av, bv, o0, 0, 0, 0);
            }
            {
                const int ncol = w * 32 + 16 + lm;
                bf16x8 bv;
                #pragma unroll
                for (int j = 0; j < 8; ++j) ((unsigned short*)&bv)[j] = KVs[kb + j][ncol];
                o1 = __builtin_amdgcn_mfma_f32_16x16x32_bf16(av, bv, o1, 0, 0, 0);
            }
        }
    }

    // ---- epilogue: residual + store (D: row=(l>>4)*4+r, col=l&15) ----
    #pragma unroll
    for (int r = 0; r < 4; ++r) {
        int row = gq * 4 + r;
        float* orow = outp + ((size_t)(b * L_SEQ + q0 + row)) * GG;
        int c0 = hh * 128 + w * 32 + lm;
        orow[1024 + c0]      = o0[r] + orow[c0];
        orow[1024 + c0 + 16] = o1[r] + orow[c0 + 16];
    }
}

// ---------------------------------------------------------------------------
extern "C" void kernel_launch(void* const* d_in, const int* in_sizes, int n_in,
                              void* d_out, int out_size, void* d_ws, size_t ws_size,
                              hipStream_t stream) {
    const float* x     = (const float*)d_in[0];
    const float* lab   = (const float*)d_in[1];
    const float* Wih_f = (const float*)d_in[2];
    const float* Whh_f = (const float*)d_in[3];
    const float* b_f   = (const float*)d_in[4];
    const float* Wih_b = (const float*)d_in[5];
    const float* Whh_b = (const float*)d_in[6];
    const float* b_b   = (const float*)d_in[7];
    const float* Wq    = (const float*)d_in[8];
    const float* bq    = (const float*)d_in[9];
    const float* Wk    = (const float*)d_in[10];
    const float* bk    = (const float*)d_in[11];
    const float* Wv    = (const float*)d_in[12];
    const float* bv    = (const float*)d_in[13];
    float* outp = (float*)d_out;
    char*  ws   = (char*)d_ws;

    // workspace layout (peak 64 MB):
    //   phase 1/2: xWf bf16 [0,32M), xWb bf16 [32M,64M)
    //   phase 3/4: Kb [0,16M), Vb [16M,32M), Qb [32M,48M)   (reuse)
    unsigned short* xWf = (unsigned short*)(ws);
    unsigned short* xWb = (unsigned short*)(ws + 33554432);
    unsigned short* Kb  = (unsigned short*)(ws);
    unsigned short* Vb  = (unsigned short*)(ws + 16777216);
    unsigned short* Qb  = (unsigned short*)(ws + 33554432);

    dim3 blk(256);
    // xW = x @ Wih^T + b  (both dirs)
    gemm_nt<<<dim3(16, 64), blk, 0, stream>>>(x, 1024, Wih_f, 1024, b_f, xWf, 2048, 0);
    gemm_nt<<<dim3(16, 64), blk, 0, stream>>>(x, 1024, Wih_b, 1024, b_b, xWb, 2048, 0);

    // zero the per-block epoch flags (d_out rows 16..17, attn half)
    hipMemsetAsync((void*)(outp + 16 * GG + 1024), 0, 4096, stream);
    hipMemsetAsync((void*)(outp + 17 * GG + 1024), 0, 4096, stream);

    // recurrence (cooperative launch for co-residency; fence-free barrier)
    void* args[] = { (void*)&Whh_f, (void*)&Whh_b, (void*)&xWf, (void*)&xWb, (void*)&outp };
    hipLaunchCooperativeKernel((const void*)lstm_coop, dim3(128), dim3(256), args, 0, stream);

    // projections (reuse xW space; stream-ordered after LSTM)
    gemm_nt<<<dim3(8, 64), blk, 0, stream>>>(lab,  1024, Wk, 1024, bk, Kb, 1024, 1);
    gemm_nt<<<dim3(8, 64), blk, 0, stream>>>(lab,  1024, Wv, 1024, bv, Vb, 1024, 1);
    gemm_nt<<<dim3(8, 64), blk, 0, stream>>>(outp, 2048, Wq, 1024, bq, Qb, 1024, 1);

    // attention + residual + concat (MFMA)
    attn_mfma<<<dim3(4096), dim3(256), 0, stream>>>(Qb, Kb, Vb, outp);
}